// Round 4
// baseline (379.284 us; speedup 1.0000x reference)
//
#include <hip/hip_runtime.h>
#include <math.h>

#define NPTS 65536
#define BATCH 32

// =====================================================================
// transpose x (B,N,2) -> x_t (N, 64)  [x_t[n][b*2+c] = x[b][n][c]]
// =====================================================================
__global__ __launch_bounds__(256) void transpose_kernel(const float* __restrict__ x,
                                                        float* __restrict__ xt)
{
    __shared__ float tile[64][65];
    int n0 = blockIdx.x * 64;
    int tid = threadIdx.x;
    int lane = tid & 63, w = tid >> 6;
    const float2* x2 = (const float2*)x;
#pragma unroll
    for (int bq = 0; bq < 8; ++bq) {
        int b = bq * 4 + w;
        float2 v = x2[(size_t)b * NPTS + n0 + lane];
        tile[lane][b * 2 + 0] = v.x;
        tile[lane][b * 2 + 1] = v.y;
    }
    __syncthreads();
#pragma unroll
    for (int rq = 0; rq < 16; ++rq) {
        int r = rq * 4 + w;
        xt[(size_t)(n0 + r) * 64 + lane] = tile[r][lane];
    }
}

// =====================================================================
// smooth: s[(i*64 + b*2+c)][n] = tanh(sum_k x_t[ord_i[clip(n-1+k)]][b*2+c]*sp_w[n,k] + sp_b[n])
// Note (i*64 + b*2 + c) == ((i*32+b)*2 + c), i.e. s is (b64, ci, N) contiguous.
// =====================================================================
__global__ __launch_bounds__(256) void smooth_kernel(const float* __restrict__ xt,
                                                     const int* __restrict__ orderings,
                                                     const float* __restrict__ sp_w,
                                                     const float* __restrict__ sp_b,
                                                     float* __restrict__ s)
{
    constexpr int TILE_N = 128;
    __shared__ int s_idx[TILE_N + 2];
    __shared__ float rows[TILE_N + 2][65];

    int bid = blockIdx.x;
    int i = bid >> 9;          // 512 tiles per SFC
    int t = bid & 511;
    int n0 = t * TILE_N;
    int tid = threadIdx.x;
    const int* ord = orderings + (size_t)i * NPTS;

    if (tid < TILE_N + 2) {
        int g = n0 - 1 + tid;
        g = g < 0 ? 0 : (g > NPTS - 1 ? NPTS - 1 : g);
        s_idx[tid] = ord[g];
    }
    __syncthreads();

    int lane = tid & 63, w = tid >> 6;
    for (int r = w; r < TILE_N + 2; r += 4)
        rows[r][lane] = xt[(size_t)s_idx[r] * 64 + lane];
    __syncthreads();

    int n_local = tid & 127;
    int half = tid >> 7;       // 0 or 1
    int n = n0 + n_local;
    float w0 = sp_w[n * 3 + 0], w1 = sp_w[n * 3 + 1], w2 = sp_w[n * 3 + 2];
    float bb = sp_b[n];
#pragma unroll 4
    for (int bc = 0; bc < 64; bc += 2) {
        int bce = bc + half;
        float v = w0 * rows[n_local][bce] + w1 * rows[n_local + 1][bce]
                + w2 * rows[n_local + 2][bce] + bb;
        s[(size_t)(i * 64 + bce) * NPTS + n] = tanhf(v);
    }
}

// =====================================================================
// Tiled strided conv1d + bias + tanh, merged batch b64 = 0..63.
// One thread per output position, CPG output channels in registers.
// Weights read from LDS with wave-uniform (broadcast) addresses.
//   thread t: l_local = t % LTILE, cg = t / LTILE, channels [cg*CPG, cg*CPG+CPG)
// =====================================================================
template <int CIN, int COUT, int LIN, int LOUT, int LTILE, bool CONCAT>
__global__ __launch_bounds__(256, 4) void conv_tiled(
    const float* __restrict__ in,      // (64, CIN, LIN)
    const float* __restrict__ w,       // (COUT, CIN, 32)
    const float* __restrict__ bias,    // (COUT,)
    float* __restrict__ out)
{
    constexpr int G = 256 / LTILE;     // channel groups
    constexpr int CPG = COUT / G;      // channels per thread
    constexpr int SPAN = 4 * LTILE + 28;
    constexpr int NT = (LOUT + LTILE - 1) / LTILE;

    __shared__ float in_s[CIN][SPAN];
    __shared__ float w_s[COUT][CIN][32];

    int bid = blockIdx.x;
    int tile = bid % NT;
    int b = bid / NT;
    int tid = threadIdx.x;

    // stage all weights (coalesced, L2-hot)
    for (int idx = tid; idx < COUT * CIN * 32; idx += 256)
        ((float*)w_s)[idx] = w[idx];

    int base = tile * LTILE * 4 - 16;
    for (int ci = 0; ci < CIN; ++ci) {
        const float* inc = in + ((size_t)b * CIN + ci) * LIN;
        for (int p = tid; p < SPAN; p += 256) {
            int pos = base + p;
            in_s[ci][p] = (pos >= 0 && pos < LIN) ? inc[pos] : 0.f;
        }
    }
    __syncthreads();

    int l_local = tid % LTILE;
    int cg = tid / LTILE;
    int l = tile * LTILE + l_local;
    int co0 = cg * CPG;

    float acc[CPG];
#pragma unroll
    for (int c = 0; c < CPG; ++c) acc[c] = bias[co0 + c];

#pragma unroll 2
    for (int ci = 0; ci < CIN; ++ci) {
#pragma unroll
        for (int k4 = 0; k4 < 8; ++k4) {
            float4 iv = *(const float4*)&in_s[ci][4 * l_local + 4 * k4];
#pragma unroll
            for (int c = 0; c < CPG; ++c) {
                float4 wv4 = *(const float4*)&w_s[co0 + c][ci][4 * k4];
                acc[c] += iv.x * wv4.x + iv.y * wv4.y + iv.z * wv4.z + iv.w * wv4.w;
            }
        }
    }

    if (l < LOUT) {
#pragma unroll
        for (int c = 0; c < CPG; ++c) {
            float r = tanhf(acc[c]);
            int co = co0 + c;
            if constexpr (CONCAT) {
                // b = i*32 + batch; feats[batch][i*1040 + co*65 + l]
                out[(size_t)(b & 31) * 2080 + (b >> 5) * 1040 + co * 65 + l] = r;
            } else {
                out[(size_t)b * (COUT * LOUT) + co * LOUT + l] = r;
            }
        }
    }
}

// =====================================================================
// fc1: (32,2080) @ (128,2080)^T + b -> tanh. One wave per output, f-parallel.
// =====================================================================
__global__ __launch_bounds__(256) void fc1_kernel(const float* __restrict__ h,
                                                  const float* __restrict__ w,
                                                  const float* __restrict__ bias,
                                                  float* __restrict__ out)
{
    int lane = threadIdx.x & 63;
    int wid = blockIdx.x * 4 + (threadIdx.x >> 6);  // 0..1023
#pragma unroll
    for (int r = 0; r < 4; ++r) {
        int o = wid + r * 1024;   // 0..4095
        int b = o >> 7;
        int j = o & 127;
        const float* hb = h + (size_t)b * 2080;
        const float* wj = w + (size_t)j * 2080;
        float acc = 0.f;
        for (int f = lane; f < 2080; f += 64) acc += hb[f] * wj[f];
        for (int off = 32; off; off >>= 1) acc += __shfl_down(acc, off, 64);
        if (lane == 0) out[b * 128 + j] = tanhf(acc + bias[j]);
    }
}

// =====================================================================
// fc2: (32,128) @ (16,128)^T + b -> tanh. One wave per output.
// =====================================================================
__global__ __launch_bounds__(256) void fc2_kernel(const float* __restrict__ h,
                                                  const float* __restrict__ w,
                                                  const float* __restrict__ bias,
                                                  float* __restrict__ out)
{
    int lane = threadIdx.x & 63;
    int o = blockIdx.x * 4 + (threadIdx.x >> 6);  // 0..511
    int b = o >> 4;
    int j = o & 15;
    const float* hb = h + (size_t)b * 128;
    const float* wj = w + (size_t)j * 128;
    float acc = hb[lane] * wj[lane] + hb[lane + 64] * wj[lane + 64];
    for (int off = 32; off; off >>= 1) acc += __shfl_down(acc, off, 64);
    if (lane == 0) out[o] = tanhf(acc + bias[j]);
}

extern "C" void kernel_launch(void* const* d_in, const int* in_sizes, int n_in,
                              void* d_out, int out_size, void* d_ws, size_t ws_size,
                              hipStream_t stream)
{
    const float* x = (const float*)d_in[0];
    const int* orderings = (const int*)d_in[1];
    const float* sp_w = (const float*)d_in[2];
    const float* sp_b = (const float*)d_in[3];
    const float* conv_w[5];
    const float* conv_b[5];
    for (int j = 0; j < 5; ++j) {
        conv_w[j] = (const float*)d_in[4 + 2 * j];
        conv_b[j] = (const float*)d_in[5 + 2 * j];
    }
    const float* fc1_w = (const float*)d_in[14];
    const float* fc1_b = (const float*)d_in[15];
    const float* fc2_w = (const float*)d_in[16];
    const float* fc2_b = (const float*)d_in[17];

    float* ws = (float*)d_ws;
    // Region A: [0, 4194560)  x_t / conv0-out ; later conv3-out + feats + h1
    // Region B: [4194560, ...) s (8,388,608) / conv1-out ; conv2-out after
    size_t o_A = 0;
    size_t o_B = 4194560;
    size_t o_c2 = o_B + 2097664;       // conv2 out after conv1 out
    size_t o_f  = o_A + 263168;        // feats after conv3 out
    size_t o_h1 = o_f + 66560;         // h1

    // 1) transpose x -> x_t
    transpose_kernel<<<NPTS / 64, 256, 0, stream>>>(x, ws + o_A);

    // 2) smooth both SFC -> s (region B), layout (b64, ci, N)
    smooth_kernel<<<2 * 512, 256, 0, stream>>>(ws + o_A, orderings, sp_w, sp_b, ws + o_B);

    // 3) conv0: (64,2,65536)->(64,4,16385)  LTILE=256, grid 64*65
    conv_tiled<2, 4, 65536, 16385, 256, false><<<64 * 65, 256, 0, stream>>>(
        ws + o_B, conv_w[0], conv_b[0], ws + o_A);

    // 4) conv1: (64,4,16385)->(64,8,4097)  LTILE=256, grid 64*17
    conv_tiled<4, 8, 16385, 4097, 256, false><<<64 * 17, 256, 0, stream>>>(
        ws + o_A, conv_w[1], conv_b[1], ws + o_B);

    // 5) conv2: (64,8,4097)->(64,16,1025)  LTILE=128, grid 64*9
    conv_tiled<8, 16, 4097, 1025, 128, false><<<64 * 9, 256, 0, stream>>>(
        ws + o_B, conv_w[2], conv_b[2], ws + o_c2);

    // 6) conv3: (64,16,1025)->(64,16,257)  LTILE=64, grid 64*5
    conv_tiled<16, 16, 1025, 257, 64, false><<<64 * 5, 256, 0, stream>>>(
        ws + o_c2, conv_w[3], conv_b[3], ws + o_A);

    // 7) conv4: (64,16,257)->(64,16,65) CONCAT  LTILE=64, grid 64*2
    conv_tiled<16, 16, 257, 65, 64, true><<<64 * 2, 256, 0, stream>>>(
        ws + o_A, conv_w[4], conv_b[4], ws + o_f);

    fc1_kernel<<<256, 256, 0, stream>>>(ws + o_f, fc1_w, fc1_b, ws + o_h1);
    fc2_kernel<<<128, 256, 0, stream>>>(ws + o_h1, fc2_w, fc2_b, (float*)d_out);
}

// Round 5
// 230.334 us; speedup vs baseline: 1.6467x; 1.6467x over previous
//
#include <hip/hip_runtime.h>
#include <math.h>

#define NPTS 65536
#define BATCH 32

// =====================================================================
// transpose x (B,N,2) -> x_t (N, 64)  [x_t[n][b*2+c] = x[b][n][c]]
// =====================================================================
__global__ __launch_bounds__(256) void transpose_kernel(const float* __restrict__ x,
                                                        float* __restrict__ xt)
{
    __shared__ float tile[64][65];
    int n0 = blockIdx.x * 64;
    int tid = threadIdx.x;
    int lane = tid & 63, w = tid >> 6;
    const float2* x2 = (const float2*)x;
#pragma unroll
    for (int bq = 0; bq < 8; ++bq) {
        int b = bq * 4 + w;
        float2 v = x2[(size_t)b * NPTS + n0 + lane];
        tile[lane][b * 2 + 0] = v.x;
        tile[lane][b * 2 + 1] = v.y;
    }
    __syncthreads();
#pragma unroll
    for (int rq = 0; rq < 16; ++rq) {
        int r = rq * 4 + w;
        xt[(size_t)(n0 + r) * 64 + lane] = tile[r][lane];
    }
}

// =====================================================================
// smooth: s[(i*64 + b*2+c)][n] = tanh(sum_k x_t[ord_i[clip(n-1+k)]][b*2+c]*sp_w[n,k] + sp_b[n])
// Note (i*64 + b*2 + c) == ((i*32+b)*2 + c), i.e. s is (b64, ci, N) contiguous.
// =====================================================================
__global__ __launch_bounds__(256) void smooth_kernel(const float* __restrict__ xt,
                                                     const int* __restrict__ orderings,
                                                     const float* __restrict__ sp_w,
                                                     const float* __restrict__ sp_b,
                                                     float* __restrict__ s)
{
    constexpr int TILE_N = 128;
    __shared__ int s_idx[TILE_N + 2];
    __shared__ float rows[TILE_N + 2][65];

    int bid = blockIdx.x;
    int i = bid >> 9;          // 512 tiles per SFC
    int t = bid & 511;
    int n0 = t * TILE_N;
    int tid = threadIdx.x;
    const int* ord = orderings + (size_t)i * NPTS;

    if (tid < TILE_N + 2) {
        int g = n0 - 1 + tid;
        g = g < 0 ? 0 : (g > NPTS - 1 ? NPTS - 1 : g);
        s_idx[tid] = ord[g];
    }
    __syncthreads();

    int lane = tid & 63, w = tid >> 6;
    for (int r = w; r < TILE_N + 2; r += 4)
        rows[r][lane] = xt[(size_t)s_idx[r] * 64 + lane];
    __syncthreads();

    int n_local = tid & 127;
    int half = tid >> 7;       // 0 or 1
    int n = n0 + n_local;
    float w0 = sp_w[n * 3 + 0], w1 = sp_w[n * 3 + 1], w2 = sp_w[n * 3 + 2];
    float bb = sp_b[n];
#pragma unroll 4
    for (int bc = 0; bc < 64; bc += 2) {
        int bce = bc + half;
        float v = w0 * rows[n_local][bce] + w1 * rows[n_local + 1][bce]
                + w2 * rows[n_local + 2][bce] + bb;
        s[(size_t)(i * 64 + bce) * NPTS + n] = tanhf(v);
    }
}

// =====================================================================
// Tiled strided conv1d + bias + tanh, merged batch b64 = 0..63.
// One thread per output position, CPG output channels in registers.
// Weights read from LDS with wave-uniform (broadcast) addresses.
// __launch_bounds__(256,2): 128-VGPR cap — enough for acc[CPG]+temps, no spill.
// =====================================================================
template <int CIN, int COUT, int LIN, int LOUT, int LTILE, bool CONCAT>
__global__ __launch_bounds__(256, 2) void conv_tiled(
    const float* __restrict__ in,      // (64, CIN, LIN)
    const float* __restrict__ w,       // (COUT, CIN, 32)
    const float* __restrict__ bias,    // (COUT,)
    float* __restrict__ out)
{
    constexpr int G = 256 / LTILE;     // channel groups
    constexpr int CPG = COUT / G;      // channels per thread
    constexpr int SPAN = 4 * LTILE + 28;
    constexpr int NT = (LOUT + LTILE - 1) / LTILE;

    __shared__ float in_s[CIN][SPAN];
    __shared__ float w_s[COUT][CIN][32];

    int bid = blockIdx.x;
    int tile = bid % NT;
    int b = bid / NT;
    int tid = threadIdx.x;

    // stage all weights (coalesced, L2-hot)
    for (int idx = tid; idx < COUT * CIN * 32; idx += 256)
        ((float*)w_s)[idx] = w[idx];

    int base = tile * LTILE * 4 - 16;
    for (int ci = 0; ci < CIN; ++ci) {
        const float* inc = in + ((size_t)b * CIN + ci) * LIN;
        for (int p = tid; p < SPAN; p += 256) {
            int pos = base + p;
            in_s[ci][p] = (pos >= 0 && pos < LIN) ? inc[pos] : 0.f;
        }
    }
    __syncthreads();

    int l_local = tid % LTILE;
    int cg = tid / LTILE;
    int l = tile * LTILE + l_local;
    int co0 = cg * CPG;

    float acc[CPG];
#pragma unroll
    for (int c = 0; c < CPG; ++c) acc[c] = bias[co0 + c];

    for (int ci = 0; ci < CIN; ++ci) {
#pragma unroll
        for (int k4 = 0; k4 < 8; ++k4) {
            float4 iv = *(const float4*)&in_s[ci][4 * l_local + 4 * k4];
#pragma unroll
            for (int c = 0; c < CPG; ++c) {
                float4 wv4 = *(const float4*)&w_s[co0 + c][ci][4 * k4];
                acc[c] += iv.x * wv4.x + iv.y * wv4.y + iv.z * wv4.z + iv.w * wv4.w;
            }
        }
    }

    if (l < LOUT) {
#pragma unroll
        for (int c = 0; c < CPG; ++c) {
            float r = tanhf(acc[c]);
            int co = co0 + c;
            if constexpr (CONCAT) {
                // b = i*32 + batch; feats[batch][i*1040 + co*65 + l]
                out[(size_t)(b & 31) * 2080 + (b >> 5) * 1040 + co * 65 + l] = r;
            } else {
                out[(size_t)b * (COUT * LOUT) + co * LOUT + l] = r;
            }
        }
    }
}

// =====================================================================
// fc1: (32,2080) @ (128,2080)^T + b -> tanh. One wave per output, f-parallel.
// =====================================================================
__global__ __launch_bounds__(256) void fc1_kernel(const float* __restrict__ h,
                                                  const float* __restrict__ w,
                                                  const float* __restrict__ bias,
                                                  float* __restrict__ out)
{
    int lane = threadIdx.x & 63;
    int wid = blockIdx.x * 4 + (threadIdx.x >> 6);  // 0..1023
#pragma unroll
    for (int r = 0; r < 4; ++r) {
        int o = wid + r * 1024;   // 0..4095
        int b = o >> 7;
        int j = o & 127;
        const float* hb = h + (size_t)b * 2080;
        const float* wj = w + (size_t)j * 2080;
        float acc = 0.f;
        for (int f = lane; f < 2080; f += 64) acc += hb[f] * wj[f];
        for (int off = 32; off; off >>= 1) acc += __shfl_down(acc, off, 64);
        if (lane == 0) out[b * 128 + j] = tanhf(acc + bias[j]);
    }
}

// =====================================================================
// fc2: (32,128) @ (16,128)^T + b -> tanh. One wave per output.
// =====================================================================
__global__ __launch_bounds__(256) void fc2_kernel(const float* __restrict__ h,
                                                  const float* __restrict__ w,
                                                  const float* __restrict__ bias,
                                                  float* __restrict__ out)
{
    int lane = threadIdx.x & 63;
    int o = blockIdx.x * 4 + (threadIdx.x >> 6);  // 0..511
    int b = o >> 4;
    int j = o & 15;
    const float* hb = h + (size_t)b * 128;
    const float* wj = w + (size_t)j * 128;
    float acc = hb[lane] * wj[lane] + hb[lane + 64] * wj[lane + 64];
    for (int off = 32; off; off >>= 1) acc += __shfl_down(acc, off, 64);
    if (lane == 0) out[o] = tanhf(acc + bias[j]);
}

extern "C" void kernel_launch(void* const* d_in, const int* in_sizes, int n_in,
                              void* d_out, int out_size, void* d_ws, size_t ws_size,
                              hipStream_t stream)
{
    const float* x = (const float*)d_in[0];
    const int* orderings = (const int*)d_in[1];
    const float* sp_w = (const float*)d_in[2];
    const float* sp_b = (const float*)d_in[3];
    const float* conv_w[5];
    const float* conv_b[5];
    for (int j = 0; j < 5; ++j) {
        conv_w[j] = (const float*)d_in[4 + 2 * j];
        conv_b[j] = (const float*)d_in[5 + 2 * j];
    }
    const float* fc1_w = (const float*)d_in[14];
    const float* fc1_b = (const float*)d_in[15];
    const float* fc2_w = (const float*)d_in[16];
    const float* fc2_b = (const float*)d_in[17];

    float* ws = (float*)d_ws;
    // Region A: [0, 4194560)  x_t / conv0-out ; later conv3-out + feats + h1
    // Region B: [4194560, ...) s (8,388,608) / conv1-out ; conv2-out after
    size_t o_A = 0;
    size_t o_B = 4194560;
    size_t o_c2 = o_B + 2097664;       // conv2 out after conv1 out
    size_t o_f  = o_A + 263168;        // feats after conv3 out
    size_t o_h1 = o_f + 66560;         // h1

    // 1) transpose x -> x_t
    transpose_kernel<<<NPTS / 64, 256, 0, stream>>>(x, ws + o_A);

    // 2) smooth both SFC -> s (region B), layout (b64, ci, N)
    smooth_kernel<<<2 * 512, 256, 0, stream>>>(ws + o_A, orderings, sp_w, sp_b, ws + o_B);

    // 3) conv0: (64,2,65536)->(64,4,16385)  LTILE=256, grid 64*65
    conv_tiled<2, 4, 65536, 16385, 256, false><<<64 * 65, 256, 0, stream>>>(
        ws + o_B, conv_w[0], conv_b[0], ws + o_A);

    // 4) conv1: (64,4,16385)->(64,8,4097)  LTILE=256, grid 64*17
    conv_tiled<4, 8, 16385, 4097, 256, false><<<64 * 17, 256, 0, stream>>>(
        ws + o_A, conv_w[1], conv_b[1], ws + o_B);

    // 5) conv2: (64,8,4097)->(64,16,1025)  LTILE=128, grid 64*9
    conv_tiled<8, 16, 4097, 1025, 128, false><<<64 * 9, 256, 0, stream>>>(
        ws + o_B, conv_w[2], conv_b[2], ws + o_c2);

    // 6) conv3: (64,16,1025)->(64,16,257)  LTILE=64, grid 64*5
    conv_tiled<16, 16, 1025, 257, 64, false><<<64 * 5, 256, 0, stream>>>(
        ws + o_c2, conv_w[3], conv_b[3], ws + o_A);

    // 7) conv4: (64,16,257)->(64,16,65) CONCAT  LTILE=64, grid 64*2
    conv_tiled<16, 16, 257, 65, 64, true><<<64 * 2, 256, 0, stream>>>(
        ws + o_A, conv_w[4], conv_b[4], ws + o_f);

    fc1_kernel<<<256, 256, 0, stream>>>(ws + o_f, fc1_w, fc1_b, ws + o_h1);
    fc2_kernel<<<128, 256, 0, stream>>>(ws + o_h1, fc2_w, fc2_b, (float*)d_out);
}